// Round 7
// baseline (141.869 us; speedup 1.0000x reference)
//
#include <hip/hip_runtime.h>
#include <hip/hip_fp16.h>

#define BB 4
#define SS 4096
#define DD 64
#define NSPLIT 8                 // K-split: 1024 blocks = 4/CU of work
#define KT_PER (SS / 64 / NSPLIT)

typedef _Float16 half8 __attribute__((ext_vector_type(8)));
typedef _Float16 half4 __attribute__((ext_vector_type(4)));
typedef __fp16 fp16x2 __attribute__((ext_vector_type(2)));   // cvt_pkrtz return type
typedef float floatx4 __attribute__((ext_vector_type(4)));
typedef float floatx16 __attribute__((ext_vector_type(16)));
typedef unsigned int uintx4 __attribute__((ext_vector_type(4)));

// Kernel A: Q = X*R, K = X*E in fp32, stored as hi/lo fp16 pairs (Markidis split).
__global__ __launch_bounds__(256) void proj_kernel(
    const float* __restrict__ X, const float* __restrict__ R, const float* __restrict__ E,
    _Float16* __restrict__ Qhi, _Float16* __restrict__ Qlo,
    _Float16* __restrict__ Khi, _Float16* __restrict__ Klo,
    _Float16* __restrict__ Vt)
{
    __shared__ float Rs[64][64];
    __shared__ float Es[64][64];
    __shared__ float Xs[16][68];     // pad 68 breaks stride-64 conflicts on transposed reads
    int t = threadIdx.x;
    long rowbase = (long)blockIdx.x * 16;

    for (int j = 0; j < 4; ++j) {
        int idx = j * 256 + t;       // 1024 float4 per 64x64 matrix
        int r = idx >> 4;
        int c = (idx & 15) * 4;
        *(float4*)&Rs[r][c] = ((const float4*)R)[idx];
        *(float4*)&Es[r][c] = ((const float4*)E)[idx];
    }
    *(float4*)&Xs[t >> 4][(t & 15) * 4] = ((const float4*)(X + rowbase * 64))[t];
    __syncthreads();

    int row = t >> 4;                // 0..15
    int c0 = (t & 15) * 4;           // 0..60
    float q[4] = {0.f, 0.f, 0.f, 0.f}, k[4] = {0.f, 0.f, 0.f, 0.f};
#pragma unroll 4
    for (int d = 0; d < 64; ++d) {
        float x = Xs[row][d];
        float4 rv = *(const float4*)&Rs[d][c0];   // ds_read_b128
        float4 ev = *(const float4*)&Es[d][c0];
        q[0] = fmaf(x, rv.x, q[0]); q[1] = fmaf(x, rv.y, q[1]);
        q[2] = fmaf(x, rv.z, q[2]); q[3] = fmaf(x, rv.w, q[3]);
        k[0] = fmaf(x, ev.x, k[0]); k[1] = fmaf(x, ev.y, k[1]);
        k[2] = fmaf(x, ev.z, k[2]); k[3] = fmaf(x, ev.w, k[3]);
    }
    long gq = (rowbase + row) * 64 + c0;
    half4 qh, ql, kh, kl;
    for (int j = 0; j < 4; ++j) {
        _Float16 h = (_Float16)q[j];
        qh[j] = h; ql[j] = (_Float16)(q[j] - (float)h);
        h = (_Float16)k[j];
        kh[j] = h; kl[j] = (_Float16)(k[j] - (float)h);
    }
    *(half4*)(Qhi + gq) = qh; *(half4*)(Qlo + gq) = ql;
    *(half4*)(Khi + gq) = kh; *(half4*)(Klo + gq) = kl;

    // V^T: Vt[b][d][s] = X[b][s][d] fp16
    int d = t >> 2;                  // 0..63
    int si = (t & 3) * 4;            // 0..12
    int b = (int)(rowbase >> 12);
    int sbase = (int)(rowbase & 4095);
    half4 v;
    for (int j = 0; j < 4; ++j) v[j] = (_Float16)Xs[si + j][d];
    *(half4*)(Vt + ((long)(b * 64 + d)) * SS + sbase + si) = v;
}

#define L2E 1.44269504088896340736f

// Kernel B: flash attention partial. 32x32x16 MFMA, S^T layout (A=K, B=Q), lane
// owns one query column; P stays in registers (permlane32_swap, T12).
// K(hi/lo) LDS-staged with XOR swizzle + 2-phase T14 pipeline.
// R6 lesson: occupancy pinned at 2 blocks/CU in BOTH R5(512blk) and R6(1024blk)
// -> per-CU resource cap (48KB LDS x3 may exceed usable pool; unified regs
// ~96+64acc+pad near the 170 = 3-waves/SIMD boundary). Fix: evict V from LDS.
// V-frag addresses depend only on (col,h) — identical across the block's 4
// waves -> direct global reads are L1-broadcast; no swizzle/ds_write needed.
// LDS 48->32KB, staged regs 24->16: targets 3 blocks/CU = 3 waves/SIMD.
__global__ __launch_bounds__(256, 2) void attn_partial(
    const _Float16* __restrict__ Qhi, const _Float16* __restrict__ Qlo,
    const _Float16* __restrict__ Khi, const _Float16* __restrict__ Klo,
    const _Float16* __restrict__ Vt,
    float* __restrict__ Op, float* __restrict__ Mp, float* __restrict__ Lp)
{
    __shared__ _Float16 KhiS[2][64][64];   // 16 KB
    __shared__ _Float16 KloS[2][64][64];   // 16 KB  (32 KB total, dbuf)

    int t = threadIdx.x;
    int w = t >> 6;                  // wave 0..3
    int lane = t & 63;
    int col = lane & 31;             // query column (QK C) == query row (PV A) == d col (PV C)
    int h = lane >> 5;               // lane half
    int l7 = lane & 7;

    // XCD-aware decode: 1024 blocks; each XCD owns 4 contiguous (b,split) K-ranges.
    int lin = blockIdx.x;            // 0..1023
    int xcd = lin & 7;
    int idx = lin >> 3;              // 0..127
    int combo = xcd * 4 + (idx >> 5);// 0..31
    int qt = idx & 31;
    int b = combo >> 3;
    int split = combo & 7;

    int q0w = qt * 128 + w * 32;

    const float scale = 0.125f * L2E;

    // Q B-fragments: B[k=dc*16+h*8+j][query=col], contiguous in Qhi[q][d]
    long qbase = ((long)b * SS + q0w + col) * DD + h * 8;
    half8 qfh[4], qfl[4];
#pragma unroll
    for (int dc = 0; dc < 4; ++dc) {
        qfh[dc] = *(const half8*)(Qhi + qbase + dc * 16);
        qfl[dc] = *(const half8*)(Qlo + qbase + dc * 16);
    }

    int kt0 = split * KT_PER;
    // staging: thread covers row=lane, 16B chunks {2w, 2w+1} of the 64x64 K tiles
    long kstage = ((long)b * SS + (long)kt0 * 64 + lane) * DD + w * 16;
    // V frags read direct from global (current tile), per-lane rows col / col+32
    long voff = ((long)b * 64 + col) * SS + kt0 * 64 + h * 8;

    // swizzled write offsets (halfs): slot delta -> ((2w+d)^(row&7))*8
    int ws0 = ((2 * w)     ^ l7) * 8;
    int ws1 = ((2 * w + 1) ^ l7) * 8;

    // prologue: issue tile-0 K staging loads
    uintx4 skh0 = *(const uintx4*)(Khi + kstage);
    uintx4 skh1 = *(const uintx4*)(Khi + kstage + 8);
    uintx4 skl0 = *(const uintx4*)(Klo + kstage);
    uintx4 skl1 = *(const uintx4*)(Klo + kstage + 8);

    floatx16 o0 = {}, o1 = {};
    float m_q = -1e30f, l_q = 0.f;

#pragma unroll 1
    for (int it = 0; it < KT_PER; ++it) {
        int buf = it & 1;
        // ds_write tile(it) into buf (compiler inserts vmcnt waits via data dep)
        *(uintx4*)&KhiS[buf][lane][ws0] = skh0;
        *(uintx4*)&KhiS[buf][lane][ws1] = skh1;
        *(uintx4*)&KloS[buf][lane][ws0] = skl0;
        *(uintx4*)&KloS[buf][lane][ws1] = skl1;
        __syncthreads();             // drain is ~free: nothing else in flight

        // issue tile(it+1) K staging (clamped reload on last iter — harmless)
        long kadv = (it + 1 < KT_PER) ? (long)64 * DD : 0;
        kstage += kadv;
        skh0 = *(const uintx4*)(Khi + kstage);
        skh1 = *(const uintx4*)(Khi + kstage + 8);
        skl0 = *(const uintx4*)(Klo + kstage);
        skl1 = *(const uintx4*)(Klo + kstage + 8);

        // S^T = K Q^T (fp32-accurate, 3-term Markidis): C[key][query=col]
        floatx16 s[2] = {};
#pragma unroll
        for (int dc = 0; dc < 4; ++dc) {
            int rs = ((dc * 2 + h) ^ l7) * 8;     // swizzled read offset
            half8 k0h = *(const half8*)&KhiS[buf][col][rs];
            half8 k1h = *(const half8*)&KhiS[buf][32 + col][rs];
            half8 k0l = *(const half8*)&KloS[buf][col][rs];
            half8 k1l = *(const half8*)&KloS[buf][32 + col][rs];
            s[0] = __builtin_amdgcn_mfma_f32_32x32x16_f16(k0h, qfh[dc], s[0], 0, 0, 0);
            s[1] = __builtin_amdgcn_mfma_f32_32x32x16_f16(k1h, qfh[dc], s[1], 0, 0, 0);
            s[0] = __builtin_amdgcn_mfma_f32_32x32x16_f16(k0h, qfl[dc], s[0], 0, 0, 0);
            s[1] = __builtin_amdgcn_mfma_f32_32x32x16_f16(k1h, qfl[dc], s[1], 0, 0, 0);
            s[0] = __builtin_amdgcn_mfma_f32_32x32x16_f16(k0l, qfh[dc], s[0], 0, 0, 0);
            s[1] = __builtin_amdgcn_mfma_f32_32x32x16_f16(k1l, qfh[dc], s[1], 0, 0, 0);
        }

        // per-query max: balanced tree (depth 5) + one partner exchange
        float mv[32];
#pragma unroll
        for (int r = 0; r < 16; ++r) { mv[r] = s[0][r]; mv[16 + r] = s[1][r]; }
#pragma unroll
        for (int st = 16; st >= 1; st >>= 1)
#pragma unroll
            for (int j = 0; j < 16; ++j)
                if (j < st) mv[j] = fmaxf(mv[j], mv[j + st]);
        float mt = fmaxf(mv[0], __shfl_xor(mv[0], 32));
        mt *= scale;

        // defer-max (T13): only rescale when some query's max grew by >8 (exp2 dom)
        if (!__all(mt <= m_q + 8.f)) {
            float mn = fmaxf(m_q, mt);
            float alpha = exp2f(m_q - mn);     // 0 on first tile
            m_q = mn;
            l_q *= alpha;
#pragma unroll
            for (int r = 0; r < 16; ++r) {     // o rows are queries: gather that query's alpha
                float a = __shfl(alpha, (r & 3) + 8 * (r >> 2) + 4 * h);
                o0[r] *= a; o1[r] *= a;
            }
        }

        // exp + fp16 pack. Lane's C rows (per kb) = keys 8g + 4h + (0..3), g=r>>2.
        float rsA = 0.f, rsB = 0.f;
        unsigned int c0[2][4], c1[2][4];       // [kb][g] = packed keys {+0,+1}, {+2,+3}
#pragma unroll
        for (int kb = 0; kb < 2; ++kb)
#pragma unroll
            for (int g = 0; g < 4; ++g) {
                float p0 = exp2f(s[kb][4 * g + 0] * scale - m_q);
                float p1 = exp2f(s[kb][4 * g + 1] * scale - m_q);
                float p2 = exp2f(s[kb][4 * g + 2] * scale - m_q);
                float p3 = exp2f(s[kb][4 * g + 3] * scale - m_q);
                rsA += p0 + p1;
                rsB += p2 + p3;
                union { fp16x2 h2; unsigned int u; } u01, u23;
                u01.h2 = __builtin_amdgcn_cvt_pkrtz(p0, p1);
                u23.h2 = __builtin_amdgcn_cvt_pkrtz(p2, p3);
                c0[kb][g] = u01.u;
                c1[kb][g] = u23.u;
            }
        float rs2 = rsA + rsB;
        rs2 += __shfl_xor(rs2, 32);
        l_q += rs2;

        // O += P V. permlane32_swap builds A-frags; V B-frags DIRECT from global
        // (addresses identical across the block's 4 waves -> L1 broadcast).
        //   ret[0] = {dst lanes 0-31 keep, lanes 32-63 get src's 0-31}
        //   ret[1] = {lanes 0-31 get dst's 32-63, lanes 32-63 keep}
#pragma unroll
        for (int kc = 0; kc < 4; ++kc) {
            int kb = kc >> 1;
            int ge = (kc & 1) * 2;
            unsigned int a0 = c0[kb][ge], b0 = c0[kb][ge + 1];
            unsigned int a1 = c1[kb][ge], b1 = c1[kb][ge + 1];
            auto r0 = __builtin_amdgcn_permlane32_swap(a0, b0, false, false);
            auto r1 = __builtin_amdgcn_permlane32_swap(a1, b1, false, false);
            union { unsigned int u[4]; half8 h8; } pa;
            pa.u[0] = (unsigned int)r0[0];   // keys h'*8 + {0,1}
            pa.u[1] = (unsigned int)r1[0];   // keys h'*8 + {2,3}
            pa.u[2] = (unsigned int)r0[1];   // keys h'*8 + {4,5}
            pa.u[3] = (unsigned int)r1[1];   // keys h'*8 + {6,7}
            half8 v0 = *(const half8*)(Vt + voff + kc * 16);
            half8 v1 = *(const half8*)(Vt + voff + (long)32 * SS + kc * 16);
            o0 = __builtin_amdgcn_mfma_f32_32x32x16_f16(pa.h8, v0, o0, 0, 0, 0);
            o1 = __builtin_amdgcn_mfma_f32_32x32x16_f16(pa.h8, v1, o1, 0, 0, 0);
        }
        voff += 64;                  // next tile's keys

        // pin staged K regs: forces completion here and stops the compiler
        // sinking the loads into the next iteration.
        asm volatile("" :: "v"(skh0), "v"(skh1), "v"(skl0), "v"(skl1));
    }

    // store unnormalized partial O (C rows = queries) and per-query (m, l)
    long pbase = ((long)b * NSPLIT + split) * SS;
    long obase = (pbase + q0w) * DD + col;
#pragma unroll
    for (int r = 0; r < 16; ++r) {
        long qrow = (r & 3) + 8 * (r >> 2) + 4 * h;
        Op[obase + qrow * DD]      = o0[r];
        Op[obase + qrow * DD + 32] = o1[r];
    }
    if (lane < 32) {
        Mp[pbase + q0w + col] = m_q;
        Lp[pbase + q0w + col] = l_q;
    }
}

// Kernel C: merge NSPLIT partials per query row. 16 queries/block.
__global__ __launch_bounds__(256) void combine_kernel(
    const float* __restrict__ Op, const float* __restrict__ Mp,
    const float* __restrict__ Lp, float* __restrict__ Out)
{
    int t = threadIdx.x;
    int qi = t >> 4;
    int d4 = (t & 15) * 4;
    long gq = (long)blockIdx.x * 16 + qi;    // global row in [0, BB*SS)
    int b = (int)(gq >> 12);
    int s = (int)(gq & 4095);

    float m = -1e30f;
    for (int i = 0; i < NSPLIT; ++i)
        m = fmaxf(m, Mp[((long)b * NSPLIT + i) * SS + s]);
    float l = 0.f;
    float4 o = {0.f, 0.f, 0.f, 0.f};
    for (int i = 0; i < NSPLIT; ++i) {
        long pb = ((long)b * NSPLIT + i) * SS + s;
        float a = exp2f(Mp[pb] - m);
        l = fmaf(Lp[pb], a, l);
        float4 oi = *(const float4*)(Op + pb * DD + d4);
        o.x = fmaf(oi.x, a, o.x); o.y = fmaf(oi.y, a, o.y);
        o.z = fmaf(oi.z, a, o.z); o.w = fmaf(oi.w, a, o.w);
    }
    float inv = 1.f / l;
    float4 r = {o.x * inv, o.y * inv, o.z * inv, o.w * inv};
    *(float4*)(Out + gq * DD + d4) = r;
}

extern "C" void kernel_launch(void* const* d_in, const int* in_sizes, int n_in,
                              void* d_out, int out_size, void* d_ws, size_t ws_size,
                              hipStream_t stream) {
    const float* X = (const float*)d_in[0];
    const float* R = (const float*)d_in[1];
    const float* E = (const float*)d_in[2];
    float* Out = (float*)d_out;

    const size_t N = (size_t)BB * SS * DD;
    _Float16* Qhi = (_Float16*)d_ws;
    _Float16* Qlo = Qhi + N;
    _Float16* Khi = Qlo + N;
    _Float16* Klo = Khi + N;
    _Float16* Vt  = Klo + N;                      // 10 MB fp16
    float* Op = (float*)(Vt + N);                 // BB*NSPLIT*SS*DD fp32 = 33.5 MB
    float* Mp = Op + (size_t)BB * NSPLIT * SS * DD;
    float* Lp = Mp + (size_t)BB * NSPLIT * SS;    // total ~44.6 MB

    proj_kernel<<<dim3(BB * SS / 16), 256, 0, stream>>>(X, R, E, Qhi, Qlo, Khi, Klo, Vt);
    attn_partial<<<dim3(BB * NSPLIT * (SS / 128)), 256, 0, stream>>>(Qhi, Qlo, Khi, Klo, Vt, Op, Mp, Lp);
    combine_kernel<<<dim3(BB * SS / 16), 256, 0, stream>>>(Op, Mp, Lp, Out);
}

// Round 8
// 122.740 us; speedup vs baseline: 1.1559x; 1.1559x over previous
//
#include <hip/hip_runtime.h>
#include <hip/hip_fp16.h>

#define BB 4
#define SS 4096
#define DD 64
#define NSPLIT 4                 // K-split: 512 blocks (R5-best; NSPLIT=8 lost twice)
#define KT_PER (SS / 64 / NSPLIT)
#define PD 72                    // LDS row pad: 144B stride -> bank-quad = (row+chunk)&7

typedef _Float16 half8 __attribute__((ext_vector_type(8)));
typedef _Float16 half4 __attribute__((ext_vector_type(4)));
typedef __fp16 fp16x2 __attribute__((ext_vector_type(2)));   // cvt_pkrtz return type
typedef float floatx4 __attribute__((ext_vector_type(4)));
typedef float floatx16 __attribute__((ext_vector_type(16)));
typedef unsigned int uintx4 __attribute__((ext_vector_type(4)));

// Kernel A: Q = X*R, K = X*E in fp32, stored as hi/lo fp16 pairs (Markidis split).
__global__ __launch_bounds__(256) void proj_kernel(
    const float* __restrict__ X, const float* __restrict__ R, const float* __restrict__ E,
    _Float16* __restrict__ Qhi, _Float16* __restrict__ Qlo,
    _Float16* __restrict__ Khi, _Float16* __restrict__ Klo,
    _Float16* __restrict__ Vt)
{
    __shared__ float Rs[64][64];
    __shared__ float Es[64][64];
    __shared__ float Xs[16][68];     // pad 68 breaks stride-64 conflicts on transposed reads
    int t = threadIdx.x;
    long rowbase = (long)blockIdx.x * 16;

    for (int j = 0; j < 4; ++j) {
        int idx = j * 256 + t;       // 1024 float4 per 64x64 matrix
        int r = idx >> 4;
        int c = (idx & 15) * 4;
        *(float4*)&Rs[r][c] = ((const float4*)R)[idx];
        *(float4*)&Es[r][c] = ((const float4*)E)[idx];
    }
    *(float4*)&Xs[t >> 4][(t & 15) * 4] = ((const float4*)(X + rowbase * 64))[t];
    __syncthreads();

    int row = t >> 4;                // 0..15
    int c0 = (t & 15) * 4;           // 0..60
    float q[4] = {0.f, 0.f, 0.f, 0.f}, k[4] = {0.f, 0.f, 0.f, 0.f};
#pragma unroll 4
    for (int d = 0; d < 64; ++d) {
        float x = Xs[row][d];
        float4 rv = *(const float4*)&Rs[d][c0];   // ds_read_b128
        float4 ev = *(const float4*)&Es[d][c0];
        q[0] = fmaf(x, rv.x, q[0]); q[1] = fmaf(x, rv.y, q[1]);
        q[2] = fmaf(x, rv.z, q[2]); q[3] = fmaf(x, rv.w, q[3]);
        k[0] = fmaf(x, ev.x, k[0]); k[1] = fmaf(x, ev.y, k[1]);
        k[2] = fmaf(x, ev.z, k[2]); k[3] = fmaf(x, ev.w, k[3]);
    }
    long gq = (rowbase + row) * 64 + c0;
    half4 qh, ql, kh, kl;
    for (int j = 0; j < 4; ++j) {
        _Float16 h = (_Float16)q[j];
        qh[j] = h; ql[j] = (_Float16)(q[j] - (float)h);
        h = (_Float16)k[j];
        kh[j] = h; kl[j] = (_Float16)(k[j] - (float)h);
    }
    *(half4*)(Qhi + gq) = qh; *(half4*)(Qlo + gq) = ql;
    *(half4*)(Khi + gq) = kh; *(half4*)(Klo + gq) = kl;

    // V^T: Vt[b][d][s] = X[b][s][d] fp16
    int d = t >> 2;                  // 0..63
    int si = (t & 3) * 4;            // 0..12
    int b = (int)(rowbase >> 12);
    int sbase = (int)(rowbase & 4095);
    half4 v;
    for (int j = 0; j < 4; ++j) v[j] = (_Float16)Xs[si + j][d];
    *(half4*)(Vt + ((long)(b * 64 + d)) * SS + sbase + si) = v;
}

#define L2E 1.44269504088896340736f

// Kernel B: flash attention partial. 32x32x16 MFMA, S^T layout (A=K, B=Q), lane
// owns one query column; P stays in registers (permlane32_swap, T12).
// K(hi/lo)+V LDS-staged, 2-phase T14 pipeline (R5 structure, measured best).
// R7 lessons: (1) V direct-global is a 32-line gather per load -> regression;
// V belongs in LDS. (2) The R5/R6 XOR swizzle was WRONG: with 128B rows, bank =
// slot*4 (row-independent) -> 8-way conflict on every ds op (the 3.1M counter).
// Fix: PD=72 pad (144B row = 36 words) -> bank-quad = (row+chunk)&7; every
// consecutive-8-lane group covers all 8 quads exactly once (writes: row=lane;
// reads: row=col). No XOR needed. 144 % 16 == 0 keeps b128 alignment.
__global__ __launch_bounds__(256, 2) void attn_partial(
    const _Float16* __restrict__ Qhi, const _Float16* __restrict__ Qlo,
    const _Float16* __restrict__ Khi, const _Float16* __restrict__ Klo,
    const _Float16* __restrict__ Vt,
    float* __restrict__ Op, float* __restrict__ Mp, float* __restrict__ Lp)
{
    __shared__ __align__(16) _Float16 KhiS[2][64][PD];   // 18 KB
    __shared__ __align__(16) _Float16 KloS[2][64][PD];   // 18 KB
    __shared__ __align__(16) _Float16 VtS [2][64][PD];   // 18 KB  (55.3 KB, dbuf)

    int t = threadIdx.x;
    int w = t >> 6;                  // wave 0..3
    int lane = t & 63;
    int col = lane & 31;             // query column (QK C) == query row (PV A) == d col (PV C)
    int h = lane >> 5;               // lane half

    // XCD-aware decode: 512 blocks; each XCD owns 2 contiguous (b,split) K-ranges.
    int lin = blockIdx.x;            // 0..511
    int xcd = lin & 7;
    int idx = lin >> 3;              // 0..63
    int combo = xcd * 2 + (idx >> 5);// 0..15
    int qt = idx & 31;
    int b = combo >> 2;
    int split = combo & 3;

    int q0w = qt * 128 + w * 32;

    const float scale = 0.125f * L2E;

    // Q B-fragments: B[k=dc*16+h*8+j][query=col], contiguous in Qhi[q][d]
    long qbase = ((long)b * SS + q0w + col) * DD + h * 8;
    half8 qfh[4], qfl[4];
#pragma unroll
    for (int dc = 0; dc < 4; ++dc) {
        qfh[dc] = *(const half8*)(Qhi + qbase + dc * 16);
        qfl[dc] = *(const half8*)(Qlo + qbase + dc * 16);
    }

    int kt0 = split * KT_PER;
    // staging: thread covers row=lane, 16B chunks {2w, 2w+1} of each 64x64 tile
    long kstage = ((long)b * SS + (long)kt0 * 64 + lane) * DD + w * 16;
    long vstage = ((long)b * 64 + lane) * SS + (long)kt0 * 64 + w * 16;

    // plain chunk offsets (halfs); padding provides the bank spread
    int ws0 = w * 16;                // chunk 2w
    int ws1 = w * 16 + 8;            // chunk 2w+1

    // prologue: issue tile-0 staging loads
    uintx4 skh0 = *(const uintx4*)(Khi + kstage);
    uintx4 skh1 = *(const uintx4*)(Khi + kstage + 8);
    uintx4 skl0 = *(const uintx4*)(Klo + kstage);
    uintx4 skl1 = *(const uintx4*)(Klo + kstage + 8);
    uintx4 sv0  = *(const uintx4*)(Vt + vstage);
    uintx4 sv1  = *(const uintx4*)(Vt + vstage + 8);

    floatx16 o0 = {}, o1 = {};
    float m_q = -1e30f, l_q = 0.f;

#pragma unroll 1
    for (int it = 0; it < KT_PER; ++it) {
        int buf = it & 1;
        // ds_write tile(it) into buf (compiler inserts vmcnt waits via data dep)
        *(uintx4*)&KhiS[buf][lane][ws0] = skh0;
        *(uintx4*)&KhiS[buf][lane][ws1] = skh1;
        *(uintx4*)&KloS[buf][lane][ws0] = skl0;
        *(uintx4*)&KloS[buf][lane][ws1] = skl1;
        *(uintx4*)&VtS [buf][lane][ws0] = sv0;
        *(uintx4*)&VtS [buf][lane][ws1] = sv1;
        __syncthreads();             // drain is ~free: nothing else in flight

        // issue tile(it+1) staging (clamped reload on last iter — harmless)
        long kadv = (it + 1 < KT_PER) ? (long)64 * DD : 0;
        long vadv = (it + 1 < KT_PER) ? 64 : 0;
        kstage += kadv; vstage += vadv;
        skh0 = *(const uintx4*)(Khi + kstage);
        skh1 = *(const uintx4*)(Khi + kstage + 8);
        skl0 = *(const uintx4*)(Klo + kstage);
        skl1 = *(const uintx4*)(Klo + kstage + 8);
        sv0  = *(const uintx4*)(Vt + vstage);
        sv1  = *(const uintx4*)(Vt + vstage + 8);

        // S^T = K Q^T (fp32-accurate, 3-term Markidis): C[key][query=col]
        floatx16 s[2] = {};
#pragma unroll
        for (int dc = 0; dc < 4; ++dc) {
            int rs = dc * 16 + h * 8;            // chunk 2dc+h
            half8 k0h = *(const half8*)&KhiS[buf][col][rs];
            half8 k1h = *(const half8*)&KhiS[buf][32 + col][rs];
            half8 k0l = *(const half8*)&KloS[buf][col][rs];
            half8 k1l = *(const half8*)&KloS[buf][32 + col][rs];
            s[0] = __builtin_amdgcn_mfma_f32_32x32x16_f16(k0h, qfh[dc], s[0], 0, 0, 0);
            s[1] = __builtin_amdgcn_mfma_f32_32x32x16_f16(k1h, qfh[dc], s[1], 0, 0, 0);
            s[0] = __builtin_amdgcn_mfma_f32_32x32x16_f16(k0h, qfl[dc], s[0], 0, 0, 0);
            s[1] = __builtin_amdgcn_mfma_f32_32x32x16_f16(k1h, qfl[dc], s[1], 0, 0, 0);
            s[0] = __builtin_amdgcn_mfma_f32_32x32x16_f16(k0l, qfh[dc], s[0], 0, 0, 0);
            s[1] = __builtin_amdgcn_mfma_f32_32x32x16_f16(k1l, qfh[dc], s[1], 0, 0, 0);
        }

        // per-query max: balanced tree (depth 5) + one partner exchange
        float mv[32];
#pragma unroll
        for (int r = 0; r < 16; ++r) { mv[r] = s[0][r]; mv[16 + r] = s[1][r]; }
#pragma unroll
        for (int st = 16; st >= 1; st >>= 1)
#pragma unroll
            for (int j = 0; j < 16; ++j)
                if (j < st) mv[j] = fmaxf(mv[j], mv[j + st]);
        float mt = fmaxf(mv[0], __shfl_xor(mv[0], 32));
        mt *= scale;

        // defer-max (T13): only rescale when some query's max grew by >8 (exp2 dom)
        if (!__all(mt <= m_q + 8.f)) {
            float mn = fmaxf(m_q, mt);
            float alpha = exp2f(m_q - mn);     // 0 on first tile
            m_q = mn;
            l_q *= alpha;
#pragma unroll
            for (int r = 0; r < 16; ++r) {     // o rows are queries: gather that query's alpha
                float a = __shfl(alpha, (r & 3) + 8 * (r >> 2) + 4 * h);
                o0[r] *= a; o1[r] *= a;
            }
        }

        // exp + fp16 pack. Lane's C rows (per kb) = keys 8g + 4h + (0..3), g=r>>2.
        float rsA = 0.f, rsB = 0.f;
        unsigned int c0[2][4], c1[2][4];       // [kb][g] = packed keys {+0,+1}, {+2,+3}
#pragma unroll
        for (int kb = 0; kb < 2; ++kb)
#pragma unroll
            for (int g = 0; g < 4; ++g) {
                float p0 = exp2f(s[kb][4 * g + 0] * scale - m_q);
                float p1 = exp2f(s[kb][4 * g + 1] * scale - m_q);
                float p2 = exp2f(s[kb][4 * g + 2] * scale - m_q);
                float p3 = exp2f(s[kb][4 * g + 3] * scale - m_q);
                rsA += p0 + p1;
                rsB += p2 + p3;
                union { fp16x2 h2; unsigned int u; } u01, u23;
                u01.h2 = __builtin_amdgcn_cvt_pkrtz(p0, p1);
                u23.h2 = __builtin_amdgcn_cvt_pkrtz(p2, p3);
                c0[kb][g] = u01.u;
                c1[kb][g] = u23.u;
            }
        float rs2 = rsA + rsB;
        rs2 += __shfl_xor(rs2, 32);
        l_q += rs2;

        // O += P V. permlane32_swap builds A-frags; V B-frags from padded LDS.
        //   ret[0] = {dst lanes 0-31 keep, lanes 32-63 get src's 0-31}
        //   ret[1] = {lanes 0-31 get dst's 32-63, lanes 32-63 keep}
#pragma unroll
        for (int kc = 0; kc < 4; ++kc) {
            int kb = kc >> 1;
            int ge = (kc & 1) * 2;
            unsigned int a0 = c0[kb][ge], b0 = c0[kb][ge + 1];
            unsigned int a1 = c1[kb][ge], b1 = c1[kb][ge + 1];
            auto r0 = __builtin_amdgcn_permlane32_swap(a0, b0, false, false);
            auto r1 = __builtin_amdgcn_permlane32_swap(a1, b1, false, false);
            union { unsigned int u[4]; half8 h8; } pa;
            pa.u[0] = (unsigned int)r0[0];   // keys h'*8 + {0,1}
            pa.u[1] = (unsigned int)r1[0];   // keys h'*8 + {2,3}
            pa.u[2] = (unsigned int)r0[1];   // keys h'*8 + {4,5}
            pa.u[3] = (unsigned int)r1[1];   // keys h'*8 + {6,7}
            int rsv = kc * 16 + h * 8;       // chunk 2kc+h
            half8 v0 = *(const half8*)&VtS[buf][col][rsv];
            half8 v1 = *(const half8*)&VtS[buf][32 + col][rsv];
            o0 = __builtin_amdgcn_mfma_f32_32x32x16_f16(pa.h8, v0, o0, 0, 0, 0);
            o1 = __builtin_amdgcn_mfma_f32_32x32x16_f16(pa.h8, v1, o1, 0, 0, 0);
        }

        // pin staged regs: forces completion here and stops the compiler
        // sinking the loads into the next iteration.
        asm volatile("" :: "v"(skh0), "v"(skh1), "v"(skl0), "v"(skl1), "v"(sv0), "v"(sv1));
    }

    // store unnormalized partial O (C rows = queries) and per-query (m, l)
    long pbase = ((long)b * NSPLIT + split) * SS;
    long obase = (pbase + q0w) * DD + col;
#pragma unroll
    for (int r = 0; r < 16; ++r) {
        long qrow = (r & 3) + 8 * (r >> 2) + 4 * h;
        Op[obase + qrow * DD]      = o0[r];
        Op[obase + qrow * DD + 32] = o1[r];
    }
    if (lane < 32) {
        Mp[pbase + q0w + col] = m_q;
        Lp[pbase + q0w + col] = l_q;
    }
}

// Kernel C: merge NSPLIT partials per query row. 16 queries/block.
__global__ __launch_bounds__(256) void combine_kernel(
    const float* __restrict__ Op, const float* __restrict__ Mp,
    const float* __restrict__ Lp, float* __restrict__ Out)
{
    int t = threadIdx.x;
    int qi = t >> 4;
    int d4 = (t & 15) * 4;
    long gq = (long)blockIdx.x * 16 + qi;    // global row in [0, BB*SS)
    int b = (int)(gq >> 12);
    int s = (int)(gq & 4095);

    float m = -1e30f;
    for (int i = 0; i < NSPLIT; ++i)
        m = fmaxf(m, Mp[((long)b * NSPLIT + i) * SS + s]);
    float l = 0.f;
    float4 o = {0.f, 0.f, 0.f, 0.f};
    for (int i = 0; i < NSPLIT; ++i) {
        long pb = ((long)b * NSPLIT + i) * SS + s;
        float a = exp2f(Mp[pb] - m);
        l = fmaf(Lp[pb], a, l);
        float4 oi = *(const float4*)(Op + pb * DD + d4);
        o.x = fmaf(oi.x, a, o.x); o.y = fmaf(oi.y, a, o.y);
        o.z = fmaf(oi.z, a, o.z); o.w = fmaf(oi.w, a, o.w);
    }
    float inv = 1.f / l;
    float4 r = {o.x * inv, o.y * inv, o.z * inv, o.w * inv};
    *(float4*)(Out + gq * DD + d4) = r;
}

extern "C" void kernel_launch(void* const* d_in, const int* in_sizes, int n_in,
                              void* d_out, int out_size, void* d_ws, size_t ws_size,
                              hipStream_t stream) {
    const float* X = (const float*)d_in[0];
    const float* R = (const float*)d_in[1];
    const float* E = (const float*)d_in[2];
    float* Out = (float*)d_out;

    const size_t N = (size_t)BB * SS * DD;
    _Float16* Qhi = (_Float16*)d_ws;
    _Float16* Qlo = Qhi + N;
    _Float16* Khi = Qlo + N;
    _Float16* Klo = Khi + N;
    _Float16* Vt  = Klo + N;                      // 10 MB fp16
    float* Op = (float*)(Vt + N);                 // BB*NSPLIT*SS*DD fp32 = 16.8 MB
    float* Mp = Op + (size_t)BB * NSPLIT * SS * DD;
    float* Lp = Mp + (size_t)BB * NSPLIT * SS;    // total ~27.3 MB

    proj_kernel<<<dim3(BB * SS / 16), 256, 0, stream>>>(X, R, E, Qhi, Qlo, Khi, Klo, Vt);
    attn_partial<<<dim3(BB * NSPLIT * (SS / 128)), 256, 0, stream>>>(Qhi, Qlo, Khi, Klo, Vt, Op, Mp, Lp);
    combine_kernel<<<dim3(BB * SS / 16), 256, 0, stream>>>(Op, Mp, Lp, Out);
}

// Round 9
// 122.705 us; speedup vs baseline: 1.1562x; 1.0003x over previous
//
#include <hip/hip_runtime.h>
#include <hip/hip_fp16.h>

#define BB 4
#define SS 4096
#define DD 64
#define NSPLIT 4                 // K-split: 512 blocks (R5/R8-best)
#define KT_PER (SS / 64 / NSPLIT)
#define PD 72                    // LDS row pad: 144B stride -> bank-quad = (row+chunk)&7

typedef _Float16 half8 __attribute__((ext_vector_type(8)));
typedef _Float16 half4 __attribute__((ext_vector_type(4)));
typedef __fp16 fp16x2 __attribute__((ext_vector_type(2)));   // cvt_pkrtz return type
typedef float floatx4 __attribute__((ext_vector_type(4)));
typedef float floatx16 __attribute__((ext_vector_type(16)));
typedef unsigned int uintx4 __attribute__((ext_vector_type(4)));

// Kernel A: Q = X*R, K = X*E in fp32, stored as hi/lo fp16 pairs (Markidis split).
__global__ __launch_bounds__(256) void proj_kernel(
    const float* __restrict__ X, const float* __restrict__ R, const float* __restrict__ E,
    _Float16* __restrict__ Qhi, _Float16* __restrict__ Qlo,
    _Float16* __restrict__ Khi, _Float16* __restrict__ Klo,
    _Float16* __restrict__ Vt)
{
    __shared__ float Rs[64][64];
    __shared__ float Es[64][64];
    __shared__ float Xs[16][68];     // pad 68 breaks stride-64 conflicts on transposed reads
    int t = threadIdx.x;
    long rowbase = (long)blockIdx.x * 16;

    for (int j = 0; j < 4; ++j) {
        int idx = j * 256 + t;       // 1024 float4 per 64x64 matrix
        int r = idx >> 4;
        int c = (idx & 15) * 4;
        *(float4*)&Rs[r][c] = ((const float4*)R)[idx];
        *(float4*)&Es[r][c] = ((const float4*)E)[idx];
    }
    *(float4*)&Xs[t >> 4][(t & 15) * 4] = ((const float4*)(X + rowbase * 64))[t];
    __syncthreads();

    int row = t >> 4;                // 0..15
    int c0 = (t & 15) * 4;           // 0..60
    float q[4] = {0.f, 0.f, 0.f, 0.f}, k[4] = {0.f, 0.f, 0.f, 0.f};
#pragma unroll 4
    for (int d = 0; d < 64; ++d) {
        float x = Xs[row][d];
        float4 rv = *(const float4*)&Rs[d][c0];   // ds_read_b128
        float4 ev = *(const float4*)&Es[d][c0];
        q[0] = fmaf(x, rv.x, q[0]); q[1] = fmaf(x, rv.y, q[1]);
        q[2] = fmaf(x, rv.z, q[2]); q[3] = fmaf(x, rv.w, q[3]);
        k[0] = fmaf(x, ev.x, k[0]); k[1] = fmaf(x, ev.y, k[1]);
        k[2] = fmaf(x, ev.z, k[2]); k[3] = fmaf(x, ev.w, k[3]);
    }
    long gq = (rowbase + row) * 64 + c0;
    half4 qh, ql, kh, kl;
    for (int j = 0; j < 4; ++j) {
        _Float16 h = (_Float16)q[j];
        qh[j] = h; ql[j] = (_Float16)(q[j] - (float)h);
        h = (_Float16)k[j];
        kh[j] = h; kl[j] = (_Float16)(k[j] - (float)h);
    }
    *(half4*)(Qhi + gq) = qh; *(half4*)(Qlo + gq) = ql;
    *(half4*)(Khi + gq) = kh; *(half4*)(Klo + gq) = kl;

    // V^T: Vt[b][d][s] = X[b][s][d] fp16
    int d = t >> 2;                  // 0..63
    int si = (t & 3) * 4;            // 0..12
    int b = (int)(rowbase >> 12);
    int sbase = (int)(rowbase & 4095);
    half4 v;
    for (int j = 0; j < 4; ++j) v[j] = (_Float16)Xs[si + j][d];
    *(half4*)(Vt + ((long)(b * 64 + d)) * SS + sbase + si) = v;
}

#define L2E 1.44269504088896340736f

// cross-half exchange on the VALU (replaces ds_bpermute __shfl_xor(x,32)):
// permlane32_swap ret[0] lanes32-63 = src lanes0-31; ret[1] lanes0-31 = dst lanes32-63.
__device__ inline float swap_half32(float x, int h) {
    union { float f; unsigned u; } a; a.f = x;
    auto r = __builtin_amdgcn_permlane32_swap(a.u, a.u, false, false);
    union { unsigned u; float f; } o;
    o.u = h ? (unsigned)r[0] : (unsigned)r[1];
    return o.f;
}

// Kernel B: flash attention partial. 32x32x16 MFMA, S^T layout (A=K, B=Q), lane
// owns one query column; P stays in registers (permlane32_swap, T12).
// K(hi/lo)+V LDS-staged (PD=72 pad, 0 bank conflicts measured R8), 2-phase T14
// pipeline with register prefetch + pin.
// R8 lesson: conflicts 3.1M->0 changed NOTHING (58.4->58.9us). Per-SIMD math:
// MfmaUtil 23%/4SIMD = 5.8% matrix-pipe busy = exactly the 8.2K cy of MFMA issue
// -> 85% of cycles neither resident wave issues: dependency-latency bound at a
// hard 2 waves/SIMD. The chains: s[0]/s[1] = 12 sequentially-dependent MFMAs.
// This round: ILP not TLP. (1) QK split into 4 chains (dc01->sA, dc23->sB,
// merged per iter); (2) PV split into 4 PERSISTENT chains (oA=kc01, oB=kc23,
// merged only at epilogue); (3) shfl_xor(..,32) -> permlane32_swap (VALU, no
// LDS-pipe/lgkm wait).
__global__ __launch_bounds__(256, 2) void attn_partial(
    const _Float16* __restrict__ Qhi, const _Float16* __restrict__ Qlo,
    const _Float16* __restrict__ Khi, const _Float16* __restrict__ Klo,
    const _Float16* __restrict__ Vt,
    float* __restrict__ Op, float* __restrict__ Mp, float* __restrict__ Lp)
{
    __shared__ __align__(16) _Float16 KhiS[2][64][PD];   // 18 KB
    __shared__ __align__(16) _Float16 KloS[2][64][PD];   // 18 KB
    __shared__ __align__(16) _Float16 VtS [2][64][PD];   // 18 KB  (55.3 KB, dbuf)

    int t = threadIdx.x;
    int w = t >> 6;                  // wave 0..3
    int lane = t & 63;
    int col = lane & 31;             // query column (QK C) == query row (PV A) == d col (PV C)
    int h = lane >> 5;               // lane half

    // XCD-aware decode: 512 blocks; each XCD owns 2 contiguous (b,split) K-ranges.
    int lin = blockIdx.x;            // 0..511
    int xcd = lin & 7;
    int idx = lin >> 3;              // 0..63
    int combo = xcd * 2 + (idx >> 5);// 0..15
    int qt = idx & 31;
    int b = combo >> 2;
    int split = combo & 3;

    int q0w = qt * 128 + w * 32;

    const float scale = 0.125f * L2E;

    // Q B-fragments: B[k=dc*16+h*8+j][query=col], contiguous in Qhi[q][d]
    long qbase = ((long)b * SS + q0w + col) * DD + h * 8;
    half8 qfh[4], qfl[4];
#pragma unroll
    for (int dc = 0; dc < 4; ++dc) {
        qfh[dc] = *(const half8*)(Qhi + qbase + dc * 16);
        qfl[dc] = *(const half8*)(Qlo + qbase + dc * 16);
    }

    int kt0 = split * KT_PER;
    // staging: thread covers row=lane, 16B chunks {2w, 2w+1} of each 64x64 tile
    long kstage = ((long)b * SS + (long)kt0 * 64 + lane) * DD + w * 16;
    long vstage = ((long)b * 64 + lane) * SS + (long)kt0 * 64 + w * 16;

    // plain chunk offsets (halfs); padding provides the bank spread
    int ws0 = w * 16;                // chunk 2w
    int ws1 = w * 16 + 8;            // chunk 2w+1

    // prologue: issue tile-0 staging loads
    uintx4 skh0 = *(const uintx4*)(Khi + kstage);
    uintx4 skh1 = *(const uintx4*)(Khi + kstage + 8);
    uintx4 skl0 = *(const uintx4*)(Klo + kstage);
    uintx4 skl1 = *(const uintx4*)(Klo + kstage + 8);
    uintx4 sv0  = *(const uintx4*)(Vt + vstage);
    uintx4 sv1  = *(const uintx4*)(Vt + vstage + 8);

    // persistent split PV accumulators (4 independent MFMA chains)
    floatx16 oA0 = {}, oA1 = {}, oB0 = {}, oB1 = {};
    float m_q = -1e30f, l_q = 0.f;

#pragma unroll 1
    for (int it = 0; it < KT_PER; ++it) {
        int buf = it & 1;
        // ds_write tile(it) into buf (compiler inserts vmcnt waits via data dep)
        *(uintx4*)&KhiS[buf][lane][ws0] = skh0;
        *(uintx4*)&KhiS[buf][lane][ws1] = skh1;
        *(uintx4*)&KloS[buf][lane][ws0] = skl0;
        *(uintx4*)&KloS[buf][lane][ws1] = skl1;
        *(uintx4*)&VtS [buf][lane][ws0] = sv0;
        *(uintx4*)&VtS [buf][lane][ws1] = sv1;
        __syncthreads();             // drain is ~free: nothing else in flight

        // issue tile(it+1) staging (clamped reload on last iter — harmless)
        long kadv = (it + 1 < KT_PER) ? (long)64 * DD : 0;
        long vadv = (it + 1 < KT_PER) ? 64 : 0;
        kstage += kadv; vstage += vadv;
        skh0 = *(const uintx4*)(Khi + kstage);
        skh1 = *(const uintx4*)(Khi + kstage + 8);
        skl0 = *(const uintx4*)(Klo + kstage);
        skl1 = *(const uintx4*)(Klo + kstage + 8);
        sv0  = *(const uintx4*)(Vt + vstage);
        sv1  = *(const uintx4*)(Vt + vstage + 8);

        // S^T = K Q^T (fp32-accurate, 3-term Markidis): C[key][query=col]
        // 4 independent accumulator chains (6-deep each instead of 12-deep).
        floatx16 sA0 = {}, sA1 = {}, sB0 = {}, sB1 = {};
#pragma unroll
        for (int dc = 0; dc < 2; ++dc) {
            int rs = dc * 16 + h * 8;            // chunk 2dc+h
            half8 k0h = *(const half8*)&KhiS[buf][col][rs];
            half8 k1h = *(const half8*)&KhiS[buf][32 + col][rs];
            half8 k0l = *(const half8*)&KloS[buf][col][rs];
            half8 k1l = *(const half8*)&KloS[buf][32 + col][rs];
            sA0 = __builtin_amdgcn_mfma_f32_32x32x16_f16(k0h, qfh[dc], sA0, 0, 0, 0);
            sA1 = __builtin_amdgcn_mfma_f32_32x32x16_f16(k1h, qfh[dc], sA1, 0, 0, 0);
            sA0 = __builtin_amdgcn_mfma_f32_32x32x16_f16(k0h, qfl[dc], sA0, 0, 0, 0);
            sA1 = __builtin_amdgcn_mfma_f32_32x32x16_f16(k1h, qfl[dc], sA1, 0, 0, 0);
            sA0 = __builtin_amdgcn_mfma_f32_32x32x16_f16(k0l, qfh[dc], sA0, 0, 0, 0);
            sA1 = __builtin_amdgcn_mfma_f32_32x32x16_f16(k1l, qfh[dc], sA1, 0, 0, 0);
        }
#pragma unroll
        for (int dc = 2; dc < 4; ++dc) {
            int rs = dc * 16 + h * 8;
            half8 k0h = *(const half8*)&KhiS[buf][col][rs];
            half8 k1h = *(const half8*)&KhiS[buf][32 + col][rs];
            half8 k0l = *(const half8*)&KloS[buf][col][rs];
            half8 k1l = *(const half8*)&KloS[buf][32 + col][rs];
            sB0 = __builtin_amdgcn_mfma_f32_32x32x16_f16(k0h, qfh[dc], sB0, 0, 0, 0);
            sB1 = __builtin_amdgcn_mfma_f32_32x32x16_f16(k1h, qfh[dc], sB1, 0, 0, 0);
            sB0 = __builtin_amdgcn_mfma_f32_32x32x16_f16(k0h, qfl[dc], sB0, 0, 0, 0);
            sB1 = __builtin_amdgcn_mfma_f32_32x32x16_f16(k1h, qfl[dc], sB1, 0, 0, 0);
            sB0 = __builtin_amdgcn_mfma_f32_32x32x16_f16(k0l, qfh[dc], sB0, 0, 0, 0);
            sB1 = __builtin_amdgcn_mfma_f32_32x32x16_f16(k1l, qfh[dc], sB1, 0, 0, 0);
        }
        floatx16 s[2];
        s[0] = sA0 + sB0;
        s[1] = sA1 + sB1;

        // per-query max: balanced tree (depth 5) + one partner exchange (VALU)
        float mv[32];
#pragma unroll
        for (int r = 0; r < 16; ++r) { mv[r] = s[0][r]; mv[16 + r] = s[1][r]; }
#pragma unroll
        for (int st = 16; st >= 1; st >>= 1)
#pragma unroll
            for (int j = 0; j < 16; ++j)
                if (j < st) mv[j] = fmaxf(mv[j], mv[j + st]);
        float mt = fmaxf(mv[0], swap_half32(mv[0], h));
        mt *= scale;

        // defer-max (T13): only rescale when some query's max grew by >8 (exp2 dom)
        if (!__all(mt <= m_q + 8.f)) {
            float mn = fmaxf(m_q, mt);
            float alpha = exp2f(m_q - mn);     // 0 on first tile
            m_q = mn;
            l_q *= alpha;
#pragma unroll
            for (int r = 0; r < 16; ++r) {     // o rows are queries: gather that query's alpha
                float a = __shfl(alpha, (r & 3) + 8 * (r >> 2) + 4 * h);
                oA0[r] *= a; oA1[r] *= a; oB0[r] *= a; oB1[r] *= a;
            }
        }

        // exp + fp16 pack. Lane's C rows (per kb) = keys 8g + 4h + (0..3), g=r>>2.
        float rsA = 0.f, rsB = 0.f;
        unsigned int c0[2][4], c1[2][4];       // [kb][g] = packed keys {+0,+1}, {+2,+3}
#pragma unroll
        for (int kb = 0; kb < 2; ++kb)
#pragma unroll
            for (int g = 0; g < 4; ++g) {
                float p0 = exp2f(s[kb][4 * g + 0] * scale - m_q);
                float p1 = exp2f(s[kb][4 * g + 1] * scale - m_q);
                float p2 = exp2f(s[kb][4 * g + 2] * scale - m_q);
                float p3 = exp2f(s[kb][4 * g + 3] * scale - m_q);
                rsA += p0 + p1;
                rsB += p2 + p3;
                union { fp16x2 h2; unsigned int u; } u01, u23;
                u01.h2 = __builtin_amdgcn_cvt_pkrtz(p0, p1);
                u23.h2 = __builtin_amdgcn_cvt_pkrtz(p2, p3);
                c0[kb][g] = u01.u;
                c1[kb][g] = u23.u;
            }
        float rs2 = rsA + rsB;
        rs2 += swap_half32(rs2, h);
        l_q += rs2;

        // O += P V. permlane32_swap builds A-frags; V B-frags from padded LDS.
        // 4 persistent chains: kc 0,1 -> oA*, kc 2,3 -> oB* (merged at epilogue).
#pragma unroll
        for (int kc = 0; kc < 4; ++kc) {
            int kb = kc >> 1;
            int ge = (kc & 1) * 2;
            unsigned int a0 = c0[kb][ge], b0 = c0[kb][ge + 1];
            unsigned int a1 = c1[kb][ge], b1 = c1[kb][ge + 1];
            auto r0 = __builtin_amdgcn_permlane32_swap(a0, b0, false, false);
            auto r1 = __builtin_amdgcn_permlane32_swap(a1, b1, false, false);
            union { unsigned int u[4]; half8 h8; } pa;
            pa.u[0] = (unsigned int)r0[0];   // keys h'*8 + {0,1}
            pa.u[1] = (unsigned int)r1[0];   // keys h'*8 + {2,3}
            pa.u[2] = (unsigned int)r0[1];   // keys h'*8 + {4,5}
            pa.u[3] = (unsigned int)r1[1];   // keys h'*8 + {6,7}
            int rsv = kc * 16 + h * 8;       // chunk 2kc+h
            half8 v0 = *(const half8*)&VtS[buf][col][rsv];
            half8 v1 = *(const half8*)&VtS[buf][32 + col][rsv];
            if (kc < 2) {
                oA0 = __builtin_amdgcn_mfma_f32_32x32x16_f16(pa.h8, v0, oA0, 0, 0, 0);
                oA1 = __builtin_amdgcn_mfma_f32_32x32x16_f16(pa.h8, v1, oA1, 0, 0, 0);
            } else {
                oB0 = __builtin_amdgcn_mfma_f32_32x32x16_f16(pa.h8, v0, oB0, 0, 0, 0);
                oB1 = __builtin_amdgcn_mfma_f32_32x32x16_f16(pa.h8, v1, oB1, 0, 0, 0);
            }
        }

        // pin staged regs: forces completion here and stops the compiler
        // sinking the loads into the next iteration.
        asm volatile("" :: "v"(skh0), "v"(skh1), "v"(skl0), "v"(skl1), "v"(sv0), "v"(sv1));
    }

    // epilogue: merge split chains, store partial O (C rows = queries) + (m,l)
    floatx16 o0 = oA0 + oB0;
    floatx16 o1 = oA1 + oB1;
    long pbase = ((long)b * NSPLIT + split) * SS;
    long obase = (pbase + q0w) * DD + col;
#pragma unroll
    for (int r = 0; r < 16; ++r) {
        long qrow = (r & 3) + 8 * (r >> 2) + 4 * h;
        Op[obase + qrow * DD]      = o0[r];
        Op[obase + qrow * DD + 32] = o1[r];
    }
    if (lane < 32) {
        Mp[pbase + q0w + col] = m_q;
        Lp[pbase + q0w + col] = l_q;
    }
}

// Kernel C: merge NSPLIT partials per query row. 16 queries/block.
__global__ __launch_bounds__(256) void combine_kernel(
    const float* __restrict__ Op, const float* __restrict__ Mp,
    const float* __restrict__ Lp, float* __restrict__ Out)
{
    int t = threadIdx.x;
    int qi = t >> 4;
    int d4 = (t & 15) * 4;
    long gq = (long)blockIdx.x * 16 + qi;    // global row in [0, BB*SS)
    int b = (int)(gq >> 12);
    int s = (int)(gq & 4095);

    float m = -1e30f;
    for (int i = 0; i < NSPLIT; ++i)
        m = fmaxf(m, Mp[((long)b * NSPLIT + i) * SS + s]);
    float l = 0.f;
    float4 o = {0.f, 0.f, 0.f, 0.f};
    for (int i = 0; i < NSPLIT; ++i) {
        long pb = ((long)b * NSPLIT + i) * SS + s;
        float a = exp2f(Mp[pb] - m);
        l = fmaf(Lp[pb], a, l);
        float4 oi = *(const float4*)(Op + pb * DD + d4);
        o.x = fmaf(oi.x, a, o.x); o.y = fmaf(oi.y, a, o.y);
        o.z = fmaf(oi.z, a, o.z); o.w = fmaf(oi.w, a, o.w);
    }
    float inv = 1.f / l;
    float4 r = {o.x * inv, o.y * inv, o.z * inv, o.w * inv};
    *(float4*)(Out + gq * DD + d4) = r;
}

extern "C" void kernel_launch(void* const* d_in, const int* in_sizes, int n_in,
                              void* d_out, int out_size, void* d_ws, size_t ws_size,
                              hipStream_t stream) {
    const float* X = (const float*)d_in[0];
    const float* R = (const float*)d_in[1];
    const float* E = (const float*)d_in[2];
    float* Out = (float*)d_out;

    const size_t N = (size_t)BB * SS * DD;
    _Float16* Qhi = (_Float16*)d_ws;
    _Float16* Qlo = Qhi + N;
    _Float16* Khi = Qlo + N;
    _Float16* Klo = Khi + N;
    _Float16* Vt  = Klo + N;                      // 10 MB fp16
    float* Op = (float*)(Vt + N);                 // BB*NSPLIT*SS*DD fp32 = 16.8 MB
    float* Mp = Op + (size_t)BB * NSPLIT * SS * DD;
    float* Lp = Mp + (size_t)BB * NSPLIT * SS;    // total ~27.3 MB

    proj_kernel<<<dim3(BB * SS / 16), 256, 0, stream>>>(X, R, E, Qhi, Qlo, Khi, Klo, Vt);
    attn_partial<<<dim3(BB * NSPLIT * (SS / 128)), 256, 0, stream>>>(Qhi, Qlo, Khi, Klo, Vt, Op, Mp, Lp);
    combine_kernel<<<dim3(BB * SS / 16), 256, 0, stream>>>(Op, Mp, Lp, Out);
}